// Round 1
// baseline (252.863 us; speedup 1.0000x reference)
//
#include <hip/hip_runtime.h>
#include <math.h>

#define EMBED   128
#define NHEADS  8
#define NPOINTS 4
#define HD      16
#define HSP     51
#define WSP     102
#define NPIX    (HSP * WSP)   // 5202
#define NQ      10000
#define NLVL    50

// ---------------------------------------------------------------------------
// Fused prep kernel, round-4 rewrite: float4 weight loads + 4 independent
// accumulator chains per lane (was: scalar loads + 1 serial chain -> latency
// pathology). FMA order per output column is unchanged (init bias, ascending
// k) so all workspace tensors are bitwise identical to the previous version.
//   blocks [0, 651)        : value projection, 8 pixels/block, 32 lanes/pixel
//   blocks [651, 651+1250) : offsets + attention, 8 queries/block
//   last block             : u = W_out @ W_proj
// ---------------------------------------------------------------------------
#define GRID_A ((NPIX + 7) / 8)   // 651
#define GRID_B (NQ / 8)           // 1250

__global__ __launch_bounds__(256) void k_prep(
    const float* __restrict__ value,
    const float* __restrict__ Wv,
    const float* __restrict__ bv,
    const float* __restrict__ query,
    const float* __restrict__ Woff,
    const float* __restrict__ boff,
    const float* __restrict__ Wattn,
    const float* __restrict__ battn,
    const float* __restrict__ Wout,
    const float* __restrict__ Wproj,
    float* __restrict__ vout,
    float* __restrict__ off_out,
    float* __restrict__ aw_out,
    float* __restrict__ u_out) {
    const int b = blockIdx.x;
    const int t = threadIdx.x;
    __shared__ float srow[8][EMBED];   // 4 KB: value rows or query rows

    if (b < GRID_A) {  // ---- value projection ----
        const int p   = t >> 5;        // pixel slot 0..7
        const int s   = t & 31;        // column group (4 cols each)
        const int pix = b * 8 + p;
        const int pl  = min(pix, NPIX - 1);   // clamp loads for the tail block
        *(float4*)&srow[p][s * 4] =
            *(const float4*)(value + (size_t)pl * EMBED + s * 4);
        __syncthreads();
        float4 acc = *(const float4*)(bv + s * 4);
        const float* vr = srow[p];
        const float* wp = Wv + s * 4;
#pragma unroll 8
        for (int k = 0; k < EMBED; ++k) {
            const float qv = vr[k];
            const float4 w4 = *(const float4*)(wp + (size_t)k * EMBED);
            acc.x = fmaf(qv, w4.x, acc.x);
            acc.y = fmaf(qv, w4.y, acc.y);
            acc.z = fmaf(qv, w4.z, acc.z);
            acc.w = fmaf(qv, w4.w, acc.w);
        }
        if (pix < NPIX) {
            const int h = s >> 2, c = (s & 3) * 4;
            *(float4*)(vout + ((size_t)h * NPIX + pix) * HD + c) = acc;
        }
    } else if (b < GRID_A + GRID_B) {  // ---- offsets + attention ----
        const int qi = t >> 5;         // query slot 0..7
        const int s  = t & 31;
        const int q  = (b - GRID_A) * 8 + qi;
        *(float4*)&srow[qi][s * 4] =
            *(const float4*)(query + (size_t)q * EMBED + s * 4);
        __syncthreads();
        if (s < 24) {                  // lanes 0-15: offsets, 16-23: attn
            const float* vr = srow[qi];
            const float* wp;
            int wstride;
            float4 acc;
            if (s < 16) {
                wp = Woff + s * 4; wstride = 64;
                acc = *(const float4*)(boff + s * 4);
            } else {
                wp = Wattn + (s - 16) * 4; wstride = 32;
                acc = *(const float4*)(battn + (s - 16) * 4);
            }
            // single loop, per-lane pointer/stride: no divergent dual-loop
#pragma unroll 8
            for (int k = 0; k < EMBED; ++k) {
                const float qv = vr[k];
                const float4 w4 = *(const float4*)(wp + (size_t)k * wstride);
                acc.x = fmaf(qv, w4.x, acc.x);
                acc.y = fmaf(qv, w4.y, acc.y);
                acc.z = fmaf(qv, w4.z, acc.z);
                acc.w = fmaf(qv, w4.w, acc.w);
            }
            if (s < 16) {
                *(float4*)(off_out + (size_t)q * 64 + s * 4) = acc;
            } else {
                // this lane holds exactly head (s-16)'s 4 logits
                const float mx = fmaxf(fmaxf(acc.x, acc.y), fmaxf(acc.z, acc.w));
                const float e0 = __expf(acc.x - mx), e1 = __expf(acc.y - mx);
                const float e2 = __expf(acc.z - mx), e3 = __expf(acc.w - mx);
                const float inv = 1.f / (e0 + e1 + e2 + e3);
                float4 r;
                r.x = e0 * inv; r.y = e1 * inv; r.z = e2 * inv; r.w = e3 * inv;
                *(float4*)(aw_out + (size_t)q * 32 + (s - 16) * 4) = r;
            }
        }
    } else {  // ---- u = W_out @ W_proj (1 block) ----
        if (t < EMBED) {
            float acc = 0.f;
#pragma unroll 8
            for (int d = 0; d < EMBED; ++d)
                acc = fmaf(Wout[(size_t)t * EMBED + d], Wproj[d], acc);
            u_out[t] = acc;
        }
    }
}

// ---------------------------------------------------------------------------
// Main kernel. 2 waves per query (levels 4-way interleaved), 2 queries per
// 256-thread block. Within a wave, the two 32-lane halves handle 2 levels per
// iteration; lane sub = h*4 + c4 owns 4 channels of head h. Cross-wave merge
// of (acc, Z, m, best) via LDS; wave 0 runs the epilogue.
// NOTE: the half-merge MUST also merge m (m = fmaxf(m, mo)) — the cross-wave
// merge consumes m as the comparison key (round-3 bug).
// ---------------------------------------------------------------------------
__global__ __launch_bounds__(256, 6) void k_main(
    const float* __restrict__ query,
    const float* __restrict__ refp,   // (NLVL, NQ, 2)
    const float* __restrict__ voff,   // (NQ, 8, 4, 2)
    const float* __restrict__ vaw,    // (NQ, 8, 4)
    const float* __restrict__ vflat,  // (8, NPIX, 16)
    const float* __restrict__ uvec,   // (128)
    const float* __restrict__ Wout,   // (128, 128)
    const float* __restrict__ bout,   // (128)
    float* __restrict__ out0,         // (NQ, 128)
    float* __restrict__ out1) {       // (NQ) argmax level, as float
    const int t = threadIdx.x;
    const int qslot = t >> 7;         // 0..1
    const int w2 = (t >> 6) & 1;      // wave index within query
    const int half = (t >> 5) & 1;
    const int sub = t & 31;
    const int h  = sub >> 2;
    const int c4 = sub & 3;
    const int q = blockIdx.x * 2 + qslot;

    __shared__ float  s_rpy[2][NLVL];
    __shared__ float4 s_acc[2][32];
    __shared__ float  s_z[2], s_m[2];
    __shared__ int    s_b[2];

    // cooperative preload of ref.y for this block's 2 queries
    if (t < 2 * NLVL) {
        const int ql = t / NLVL, l = t - ql * NLVL;
        const int qq = blockIdx.x * 2 + ql;
        s_rpy[ql][l] = refp[((size_t)l * NQ + qq) * 2 + 1];
    }

    const float4* offp = (const float4*)(voff + (size_t)q * 64 + h * 8);
    const float4 o01 = offp[0];       // p0.x p0.y p1.x p1.y
    const float4 o23 = offp[1];
    const float4 awv4 = *(const float4*)(vaw + (size_t)q * 32 + h * 4);
    const float4 u4 = *(const float4*)(uvec + h * 16 + c4 * 4);
    const float rpx = refp[(size_t)q * 2];   // col is level-invariant
    const float4* vbase = (const float4*)vflat + (size_t)h * NPIX * 4 + c4;

    const float offx[4] = {o01.x, o01.z, o23.x, o23.z};
    const float offy[4] = {o01.y, o01.w, o23.y, o23.w};
    const float awv[4]  = {awv4.x, awv4.y, awv4.z, awv4.w};

    // level-independent x-axis state per point
    float wx0[NPOINTS], wx1[NPOINTS], oyc[NPOINTS];
    int xo0[NPOINTS], xo1[NPOINTS];
#pragma unroll
    for (int p = 0; p < NPOINTS; ++p) {
        const float px = fmaf(rpx, (float)WSP, offx[p]) - 0.5f;
        const float fx = floorf(px);
        const float dx = px - fx;
        const int x0 = (int)fx, x1 = x0 + 1;
        const float a = awv[p];
        wx0[p] = ((unsigned)x0 < (unsigned)WSP) ? a * (1.f - dx) : 0.f;
        wx1[p] = ((unsigned)x1 < (unsigned)WSP) ? a * dx : 0.f;
        xo0[p] = min(max(x0, 0), WSP - 1) * 4;
        xo1[p] = min(max(x1, 0), WSP - 1) * 4;
        oyc[p] = offy[p] - 0.5f;
    }

    __syncthreads();

    float4 acc = {0.f, 0.f, 0.f, 0.f};
    float Z = 0.f, m = -1e30f;
    int best = 0;

#pragma unroll 1
    for (int i = 0; i < 13; ++i) {
        if (4 * i + (w2 << 1) >= NLVL) break;   // wave-uniform (depends on w2 only)
        const int l = 4 * i + (w2 << 1) + half;
        const float rpy = s_rpy[qslot][l];
        float4 s = {0.f, 0.f, 0.f, 0.f};
#pragma unroll
        for (int p = 0; p < NPOINTS; ++p) {
            const float py = fmaf(rpy, (float)HSP, oyc[p]);
            const float fy = floorf(py);
            const float dy = py - fy;
            const int y0 = (int)fy, y1 = y0 + 1;
            const float t0 = ((unsigned)y0 < (unsigned)HSP) ? (1.f - dy) : 0.f;
            const float t1 = ((unsigned)y1 < (unsigned)HSP) ? dy : 0.f;
            const int rb0 = min(max(y0, 0), HSP - 1) * (WSP * 4);
            const int rb1 = min(max(y1, 0), HSP - 1) * (WSP * 4);
            const float w00 = wx0[p] * t0;
            const float w01 = wx1[p] * t0;
            const float w10 = wx0[p] * t1;
            const float w11 = wx1[p] * t1;
            const float4 v00 = vbase[rb0 + xo0[p]];
            const float4 v01 = vbase[rb0 + xo1[p]];
            const float4 v10 = vbase[rb1 + xo0[p]];
            const float4 v11 = vbase[rb1 + xo1[p]];
            s.x = fmaf(w00, v00.x, s.x); s.y = fmaf(w00, v00.y, s.y);
            s.z = fmaf(w00, v00.z, s.z); s.w = fmaf(w00, v00.w, s.w);
            s.x = fmaf(w01, v01.x, s.x); s.y = fmaf(w01, v01.y, s.y);
            s.z = fmaf(w01, v01.z, s.z); s.w = fmaf(w01, v01.w, s.w);
            s.x = fmaf(w10, v10.x, s.x); s.y = fmaf(w10, v10.y, s.y);
            s.z = fmaf(w10, v10.z, s.z); s.w = fmaf(w10, v10.w, s.w);
            s.x = fmaf(w11, v11.x, s.x); s.y = fmaf(w11, v11.y, s.y);
            s.z = fmaf(w11, v11.z, s.z); s.w = fmaf(w11, v11.w, s.w);
        }
        // logit = samp_agg . u, reduced over the 32 lanes of this half
        float part = s.x * u4.x;
        part = fmaf(s.y, u4.y, part);
        part = fmaf(s.z, u4.z, part);
        part = fmaf(s.w, u4.w, part);
#pragma unroll
        for (int d = 1; d < 32; d <<= 1)
            part += __shfl_xor(part, d, 64);
        const float e = __expf(part);
        Z += e;
        acc.x = fmaf(e, s.x, acc.x);
        acc.y = fmaf(e, s.y, acc.y);
        acc.z = fmaf(e, s.z, acc.z);
        acc.w = fmaf(e, s.w, acc.w);
        best = (part > m) ? l : best;   // strict > : first occurrence wins
        m = fmaxf(part, m);
    }

    // merge the two halves of this wave (exact: plain sums, no rescale)
    {
        const float mo = __shfl_xor(m, 32, 64);
        const int   bo = __shfl_xor(best, 32, 64);
        const float Zo = __shfl_xor(Z, 32, 64);
        const float ax = __shfl_xor(acc.x, 32, 64);
        const float ay = __shfl_xor(acc.y, 32, 64);
        const float az = __shfl_xor(acc.z, 32, 64);
        const float aw_ = __shfl_xor(acc.w, 32, 64);
        const bool takeOther = (mo > m) || (mo == m && bo < best);
        best = takeOther ? bo : best;
        m = fmaxf(m, mo);               // <- the round-3 fix: merge the key too
        Z += Zo;
        acc.x += ax; acc.y += ay; acc.z += az; acc.w += aw_;
    }

    // wave 1 publishes its partials; wave 0 merges and finishes
    if (w2 == 1) {
        if (half == 0) s_acc[qslot][sub] = acc;
        if ((t & 63) == 0) { s_z[qslot] = Z; s_m[qslot] = m; s_b[qslot] = best; }
    }
    __syncthreads();

    if (w2 == 0) {
        const float4 ao = s_acc[qslot][sub];
        const float Zo = s_z[qslot];
        const float mo = s_m[qslot];
        const int   bo = s_b[qslot];
        const bool takeOther = (mo > m) || (mo == m && bo < best);
        best = takeOther ? bo : best;
        Z += Zo;
        acc.x += ao.x; acc.y += ao.y; acc.z += ao.z; acc.w += ao.w;

        const float inv = 1.f / Z;
        if (half == 0) {
            float4 sv;
            sv.x = acc.x * inv; sv.y = acc.y * inv;
            sv.z = acc.z * inv; sv.w = acc.w * inv;
            s_acc[qslot][sub] = sv;       // channel-group index == sub
            if (sub == 0) out1[q] = (float)best;
        }
        // same-wave DS ordering makes the write visible to both halves below

        // final: out[dp] = sum_c s[c]*Wout[c][dp] + bout[dp] + 2*query[q][dp]
        // split-K across the two halves: half0 sums cg 0..15, half1 cg 16..31
        const int dpb = sub * 4;
        float4 r = {0.f, 0.f, 0.f, 0.f};
        if (half == 0) {
            const float4 b4 = *(const float4*)(bout + dpb);
            const float4 q4 = *(const float4*)(query + (size_t)q * EMBED + dpb);
            r.x = fmaf(2.f, q4.x, b4.x);
            r.y = fmaf(2.f, q4.y, b4.y);
            r.z = fmaf(2.f, q4.z, b4.z);
            r.w = fmaf(2.f, q4.w, b4.w);
        }
        const float4* srow = s_acc[qslot];
        const int cg0 = half * 16;
#pragma unroll 4
        for (int cg = cg0; cg < cg0 + 16; ++cg) {
            const float4 s4 = srow[cg];
            const float4 w0 = *(const float4*)(Wout + (size_t)(cg * 4 + 0) * EMBED + dpb);
            const float4 w1 = *(const float4*)(Wout + (size_t)(cg * 4 + 1) * EMBED + dpb);
            const float4 w2v = *(const float4*)(Wout + (size_t)(cg * 4 + 2) * EMBED + dpb);
            const float4 w3 = *(const float4*)(Wout + (size_t)(cg * 4 + 3) * EMBED + dpb);
            r.x = fmaf(s4.x, w0.x, r.x); r.y = fmaf(s4.x, w0.y, r.y);
            r.z = fmaf(s4.x, w0.z, r.z); r.w = fmaf(s4.x, w0.w, r.w);
            r.x = fmaf(s4.y, w1.x, r.x); r.y = fmaf(s4.y, w1.y, r.y);
            r.z = fmaf(s4.y, w1.z, r.z); r.w = fmaf(s4.y, w1.w, r.w);
            r.x = fmaf(s4.z, w2v.x, r.x); r.y = fmaf(s4.z, w2v.y, r.y);
            r.z = fmaf(s4.z, w2v.z, r.z); r.w = fmaf(s4.z, w2v.w, r.w);
            r.x = fmaf(s4.w, w3.x, r.x); r.y = fmaf(s4.w, w3.y, r.y);
            r.z = fmaf(s4.w, w3.z, r.z); r.w = fmaf(s4.w, w3.w, r.w);
        }
        // combine the two half-sums and store from half 0
        {
            const float rx = __shfl_xor(r.x, 32, 64);
            const float ry = __shfl_xor(r.y, 32, 64);
            const float rz = __shfl_xor(r.z, 32, 64);
            const float rw = __shfl_xor(r.w, 32, 64);
            r.x += rx; r.y += ry; r.z += rz; r.w += rw;
        }
        if (half == 0)
            *(float4*)(out0 + (size_t)q * EMBED + dpb) = r;
    }
}

// ---------------------------------------------------------------------------
extern "C" void kernel_launch(void* const* d_in, const int* in_sizes, int n_in,
                              void* d_out, int out_size, void* d_ws, size_t ws_size,
                              hipStream_t stream) {
    const float* query = (const float*)d_in[0];
    const float* value = (const float*)d_in[1];
    const float* refp  = (const float*)d_in[2];
    const float* Woff  = (const float*)d_in[3];
    const float* boff  = (const float*)d_in[4];
    const float* Wattn = (const float*)d_in[5];
    const float* battn = (const float*)d_in[6];
    const float* Wval  = (const float*)d_in[7];
    const float* bval  = (const float*)d_in[8];
    const float* Wout  = (const float*)d_in[9];
    const float* bout  = (const float*)d_in[10];
    const float* Wproj = (const float*)d_in[11];
    // d_in[12] = b_proj: level-constant -> cancels in softmax/argmax, unused.

    float* ws = (float*)d_ws;
    float* ws_v   = ws;                                   // 8*5202*16
    float* ws_off = ws_v + (size_t)NHEADS * NPIX * HD;    // NQ*64
    float* ws_aw  = ws_off + (size_t)NQ * 64;             // NQ*32
    float* ws_u   = ws_aw + (size_t)NQ * 32;              // 128

    float* out0 = (float*)d_out;
    float* out1 = out0 + (size_t)NQ * EMBED;

    hipLaunchKernelGGL(k_prep, dim3(GRID_A + GRID_B + 1), dim3(256), 0, stream,
                       value, Wval, bval, query, Woff, boff, Wattn, battn,
                       Wout, Wproj, ws_v, ws_off, ws_aw, ws_u);
    hipLaunchKernelGGL(k_main, dim3(NQ / 2), dim3(256), 0, stream,
                       query, refp, ws_off, ws_aw, ws_v, ws_u, Wout, bout,
                       out0, out1);
}

// Round 2
// 250.524 us; speedup vs baseline: 1.0093x; 1.0093x over previous
//
#include <hip/hip_runtime.h>
#include <math.h>

#define EMBED   128
#define NHEADS  8
#define NPOINTS 4
#define HD      16
#define HSP     51
#define WSP     102
#define NPIX    (HSP * WSP)   // 5202
#define NQ      10000
#define NLVL    50

// ---------------------------------------------------------------------------
// Fused prep kernel. float4 weight loads + 4 independent accumulator chains
// per lane. FMA order per output column: init bias, ascending k (bitwise
// stable across rounds).
// Round-5: vout layout changed to PIXEL-MAJOR (pix, 128) so k_main's gather
// clusters into contiguous 512 B pixel records (was (h, pix, 16): 8 scattered
// 64 B segments per wave-load).
//   blocks [0, 651)        : value projection, 8 pixels/block, 32 lanes/pixel
//   blocks [651, 651+1250) : offsets + attention, 8 queries/block
//   last block             : u = W_out @ W_proj
// ---------------------------------------------------------------------------
#define GRID_A ((NPIX + 7) / 8)   // 651
#define GRID_B (NQ / 8)           // 1250

__global__ __launch_bounds__(256) void k_prep(
    const float* __restrict__ value,
    const float* __restrict__ Wv,
    const float* __restrict__ bv,
    const float* __restrict__ query,
    const float* __restrict__ Woff,
    const float* __restrict__ boff,
    const float* __restrict__ Wattn,
    const float* __restrict__ battn,
    const float* __restrict__ Wout,
    const float* __restrict__ Wproj,
    float* __restrict__ vout,
    float* __restrict__ off_out,
    float* __restrict__ aw_out,
    float* __restrict__ u_out) {
    const int b = blockIdx.x;
    const int t = threadIdx.x;
    __shared__ float srow[8][EMBED];   // 4 KB: value rows or query rows

    if (b < GRID_A) {  // ---- value projection ----
        const int p   = t >> 5;        // pixel slot 0..7
        const int s   = t & 31;        // column group (4 cols each)
        const int pix = b * 8 + p;
        const int pl  = min(pix, NPIX - 1);   // clamp loads for the tail block
        *(float4*)&srow[p][s * 4] =
            *(const float4*)(value + (size_t)pl * EMBED + s * 4);
        __syncthreads();
        float4 acc = *(const float4*)(bv + s * 4);
        const float* vr = srow[p];
        const float* wp = Wv + s * 4;
#pragma unroll 8
        for (int k = 0; k < EMBED; ++k) {
            const float qv = vr[k];
            const float4 w4 = *(const float4*)(wp + (size_t)k * EMBED);
            acc.x = fmaf(qv, w4.x, acc.x);
            acc.y = fmaf(qv, w4.y, acc.y);
            acc.z = fmaf(qv, w4.z, acc.z);
            acc.w = fmaf(qv, w4.w, acc.w);
        }
        if (pix < NPIX) {
            // pixel-major: vout[pix][col], col = s*4 .. s*4+3
            *(float4*)(vout + (size_t)pix * EMBED + s * 4) = acc;
        }
    } else if (b < GRID_A + GRID_B) {  // ---- offsets + attention ----
        const int qi = t >> 5;         // query slot 0..7
        const int s  = t & 31;
        const int q  = (b - GRID_A) * 8 + qi;
        *(float4*)&srow[qi][s * 4] =
            *(const float4*)(query + (size_t)q * EMBED + s * 4);
        __syncthreads();
        if (s < 24) {                  // lanes 0-15: offsets, 16-23: attn
            const float* vr = srow[qi];
            const float* wp;
            int wstride;
            float4 acc;
            if (s < 16) {
                wp = Woff + s * 4; wstride = 64;
                acc = *(const float4*)(boff + s * 4);
            } else {
                wp = Wattn + (s - 16) * 4; wstride = 32;
                acc = *(const float4*)(battn + (s - 16) * 4);
            }
#pragma unroll 8
            for (int k = 0; k < EMBED; ++k) {
                const float qv = vr[k];
                const float4 w4 = *(const float4*)(wp + (size_t)k * wstride);
                acc.x = fmaf(qv, w4.x, acc.x);
                acc.y = fmaf(qv, w4.y, acc.y);
                acc.z = fmaf(qv, w4.z, acc.z);
                acc.w = fmaf(qv, w4.w, acc.w);
            }
            if (s < 16) {
                *(float4*)(off_out + (size_t)q * 64 + s * 4) = acc;
            } else {
                const float mx = fmaxf(fmaxf(acc.x, acc.y), fmaxf(acc.z, acc.w));
                const float e0 = __expf(acc.x - mx), e1 = __expf(acc.y - mx);
                const float e2 = __expf(acc.z - mx), e3 = __expf(acc.w - mx);
                const float inv = 1.f / (e0 + e1 + e2 + e3);
                float4 r;
                r.x = e0 * inv; r.y = e1 * inv; r.z = e2 * inv; r.w = e3 * inv;
                *(float4*)(aw_out + (size_t)q * 32 + (s - 16) * 4) = r;
            }
        }
    } else {  // ---- u = W_out @ W_proj (1 block) ----
        if (t < EMBED) {
            float acc = 0.f;
#pragma unroll 8
            for (int d = 0; d < EMBED; ++d)
                acc = fmaf(Wout[(size_t)t * EMBED + d], Wproj[d], acc);
            u_out[t] = acc;
        }
    }
}

// ---------------------------------------------------------------------------
// Main kernel. 2 waves per query (levels 4-way interleaved), 2 queries per
// 256-thread block. Within a wave, the two 32-lane halves handle 2 levels per
// iteration; lane sub = h*4 + c4 owns 4 channels of head h.
// Round-5: vflat is pixel-major (pix, 128). A pixel record is 512 B
// contiguous; all 32 lanes of a half gather within the same few-pixel
// neighborhood (offsets ~ +-1 px) -> ~1-2 contiguous segments per wave-load
// instead of 8 scattered ones. All 16 corner loads are staged into registers
// before the FMA block (launch_bounds relaxed to 4 waves/EU for the VGPRs).
// NOTE: the half-merge MUST also merge m (m = fmaxf(m, mo)) — the cross-wave
// merge consumes m as the comparison key (round-3 bug).
// ---------------------------------------------------------------------------
__global__ __launch_bounds__(256, 4) void k_main(
    const float* __restrict__ query,
    const float* __restrict__ refp,   // (NLVL, NQ, 2)
    const float* __restrict__ voff,   // (NQ, 8, 4, 2)
    const float* __restrict__ vaw,    // (NQ, 8, 4)
    const float* __restrict__ vflat,  // (NPIX, 128) pixel-major
    const float* __restrict__ uvec,   // (128)
    const float* __restrict__ Wout,   // (128, 128)
    const float* __restrict__ bout,   // (128)
    float* __restrict__ out0,         // (NQ, 128)
    float* __restrict__ out1) {       // (NQ) argmax level, as float
    const int t = threadIdx.x;
    const int qslot = t >> 7;         // 0..1
    const int w2 = (t >> 6) & 1;      // wave index within query
    const int half = (t >> 5) & 1;
    const int sub = t & 31;
    const int h  = sub >> 2;
    const int c4 = sub & 3;
    const int q = blockIdx.x * 2 + qslot;

    __shared__ float  s_rpy[2][NLVL];
    __shared__ float4 s_acc[2][32];
    __shared__ float  s_z[2], s_m[2];
    __shared__ int    s_b[2];

    // cooperative preload of ref.y for this block's 2 queries
    if (t < 2 * NLVL) {
        const int ql = t / NLVL, l = t - ql * NLVL;
        const int qq = blockIdx.x * 2 + ql;
        s_rpy[ql][l] = refp[((size_t)l * NQ + qq) * 2 + 1];
    }

    const float4* offp = (const float4*)(voff + (size_t)q * 64 + h * 8);
    const float4 o01 = offp[0];       // p0.x p0.y p1.x p1.y
    const float4 o23 = offp[1];
    const float4 awv4 = *(const float4*)(vaw + (size_t)q * 32 + h * 4);
    const float4 u4 = *(const float4*)(uvec + h * 16 + c4 * 4);
    const float rpx = refp[(size_t)q * 2];   // col is level-invariant
    // lane-fixed channel slot within a 32-float4 pixel record
    const float4* vbase = (const float4*)vflat + h * 4 + c4;

    const float offx[4] = {o01.x, o01.z, o23.x, o23.z};
    const float offy[4] = {o01.y, o01.w, o23.y, o23.w};
    const float awv[4]  = {awv4.x, awv4.y, awv4.z, awv4.w};

    // level-independent x-axis state per point (pixel stride = 32 float4)
    float wx0[NPOINTS], wx1[NPOINTS], oyc[NPOINTS];
    int xo0[NPOINTS], xo1[NPOINTS];
#pragma unroll
    for (int p = 0; p < NPOINTS; ++p) {
        const float px = fmaf(rpx, (float)WSP, offx[p]) - 0.5f;
        const float fx = floorf(px);
        const float dx = px - fx;
        const int x0 = (int)fx, x1 = x0 + 1;
        const float a = awv[p];
        wx0[p] = ((unsigned)x0 < (unsigned)WSP) ? a * (1.f - dx) : 0.f;
        wx1[p] = ((unsigned)x1 < (unsigned)WSP) ? a * dx : 0.f;
        xo0[p] = min(max(x0, 0), WSP - 1) * 32;
        xo1[p] = min(max(x1, 0), WSP - 1) * 32;
        oyc[p] = offy[p] - 0.5f;
    }

    __syncthreads();

    float4 acc = {0.f, 0.f, 0.f, 0.f};
    float Z = 0.f, m = -1e30f;
    int best = 0;

#pragma unroll 1
    for (int i = 0; i < 13; ++i) {
        if (4 * i + (w2 << 1) >= NLVL) break;   // wave-uniform (depends on w2 only)
        const int l = 4 * i + (w2 << 1) + half;
        const float rpy = s_rpy[qslot][l];

        // ---- stage: issue all 16 corner loads, then consume ----
        float4 v00[NPOINTS], v01[NPOINTS], v10[NPOINTS], v11[NPOINTS];
        float w00[NPOINTS], w01[NPOINTS], w10[NPOINTS], w11[NPOINTS];
#pragma unroll
        for (int p = 0; p < NPOINTS; ++p) {
            const float py = fmaf(rpy, (float)HSP, oyc[p]);
            const float fy = floorf(py);
            const float dy = py - fy;
            const int y0 = (int)fy, y1 = y0 + 1;
            const float t0 = ((unsigned)y0 < (unsigned)HSP) ? (1.f - dy) : 0.f;
            const float t1 = ((unsigned)y1 < (unsigned)HSP) ? dy : 0.f;
            const int rb0 = min(max(y0, 0), HSP - 1) * (WSP * 32);
            const int rb1 = min(max(y1, 0), HSP - 1) * (WSP * 32);
            v00[p] = vbase[rb0 + xo0[p]];
            v01[p] = vbase[rb0 + xo1[p]];
            v10[p] = vbase[rb1 + xo0[p]];
            v11[p] = vbase[rb1 + xo1[p]];
            w00[p] = wx0[p] * t0;
            w01[p] = wx1[p] * t0;
            w10[p] = wx0[p] * t1;
            w11[p] = wx1[p] * t1;
        }
        float4 s = {0.f, 0.f, 0.f, 0.f};
#pragma unroll
        for (int p = 0; p < NPOINTS; ++p) {
            s.x = fmaf(w00[p], v00[p].x, s.x); s.y = fmaf(w00[p], v00[p].y, s.y);
            s.z = fmaf(w00[p], v00[p].z, s.z); s.w = fmaf(w00[p], v00[p].w, s.w);
            s.x = fmaf(w01[p], v01[p].x, s.x); s.y = fmaf(w01[p], v01[p].y, s.y);
            s.z = fmaf(w01[p], v01[p].z, s.z); s.w = fmaf(w01[p], v01[p].w, s.w);
            s.x = fmaf(w10[p], v10[p].x, s.x); s.y = fmaf(w10[p], v10[p].y, s.y);
            s.z = fmaf(w10[p], v10[p].z, s.z); s.w = fmaf(w10[p], v10[p].w, s.w);
            s.x = fmaf(w11[p], v11[p].x, s.x); s.y = fmaf(w11[p], v11[p].y, s.y);
            s.z = fmaf(w11[p], v11[p].z, s.z); s.w = fmaf(w11[p], v11[p].w, s.w);
        }
        // logit = samp_agg . u, reduced over the 32 lanes of this half
        float part = s.x * u4.x;
        part = fmaf(s.y, u4.y, part);
        part = fmaf(s.z, u4.z, part);
        part = fmaf(s.w, u4.w, part);
#pragma unroll
        for (int d = 1; d < 32; d <<= 1)
            part += __shfl_xor(part, d, 64);
        const float e = __expf(part);
        Z += e;
        acc.x = fmaf(e, s.x, acc.x);
        acc.y = fmaf(e, s.y, acc.y);
        acc.z = fmaf(e, s.z, acc.z);
        acc.w = fmaf(e, s.w, acc.w);
        best = (part > m) ? l : best;   // strict > : first occurrence wins
        m = fmaxf(part, m);
    }

    // merge the two halves of this wave (exact: plain sums, no rescale)
    {
        const float mo = __shfl_xor(m, 32, 64);
        const int   bo = __shfl_xor(best, 32, 64);
        const float Zo = __shfl_xor(Z, 32, 64);
        const float ax = __shfl_xor(acc.x, 32, 64);
        const float ay = __shfl_xor(acc.y, 32, 64);
        const float az = __shfl_xor(acc.z, 32, 64);
        const float aw_ = __shfl_xor(acc.w, 32, 64);
        const bool takeOther = (mo > m) || (mo == m && bo < best);
        best = takeOther ? bo : best;
        m = fmaxf(m, mo);               // <- merge the key too (round-3 fix)
        Z += Zo;
        acc.x += ax; acc.y += ay; acc.z += az; acc.w += aw_;
    }

    // wave 1 publishes its partials; wave 0 merges and finishes
    if (w2 == 1) {
        if (half == 0) s_acc[qslot][sub] = acc;
        if ((t & 63) == 0) { s_z[qslot] = Z; s_m[qslot] = m; s_b[qslot] = best; }
    }
    __syncthreads();

    if (w2 == 0) {
        const float4 ao = s_acc[qslot][sub];
        const float Zo = s_z[qslot];
        const float mo = s_m[qslot];
        const int   bo = s_b[qslot];
        const bool takeOther = (mo > m) || (mo == m && bo < best);
        best = takeOther ? bo : best;
        Z += Zo;
        acc.x += ao.x; acc.y += ao.y; acc.z += ao.z; acc.w += ao.w;

        const float inv = 1.f / Z;
        if (half == 0) {
            float4 sv;
            sv.x = acc.x * inv; sv.y = acc.y * inv;
            sv.z = acc.z * inv; sv.w = acc.w * inv;
            s_acc[qslot][sub] = sv;       // channel-group index == sub
            if (sub == 0) out1[q] = (float)best;
        }
        // same-wave DS ordering makes the write visible to both halves below

        // final: out[dp] = sum_c s[c]*Wout[c][dp] + bout[dp] + 2*query[q][dp]
        // split-K across the two halves: half0 sums cg 0..15, half1 cg 16..31
        const int dpb = sub * 4;
        float4 r = {0.f, 0.f, 0.f, 0.f};
        if (half == 0) {
            const float4 b4 = *(const float4*)(bout + dpb);
            const float4 q4 = *(const float4*)(query + (size_t)q * EMBED + dpb);
            r.x = fmaf(2.f, q4.x, b4.x);
            r.y = fmaf(2.f, q4.y, b4.y);
            r.z = fmaf(2.f, q4.z, b4.z);
            r.w = fmaf(2.f, q4.w, b4.w);
        }
        const float4* srow = s_acc[qslot];
        const int cg0 = half * 16;
#pragma unroll 4
        for (int cg = cg0; cg < cg0 + 16; ++cg) {
            const float4 s4 = srow[cg];
            const float4 w0 = *(const float4*)(Wout + (size_t)(cg * 4 + 0) * EMBED + dpb);
            const float4 w1 = *(const float4*)(Wout + (size_t)(cg * 4 + 1) * EMBED + dpb);
            const float4 w2v = *(const float4*)(Wout + (size_t)(cg * 4 + 2) * EMBED + dpb);
            const float4 w3 = *(const float4*)(Wout + (size_t)(cg * 4 + 3) * EMBED + dpb);
            r.x = fmaf(s4.x, w0.x, r.x); r.y = fmaf(s4.x, w0.y, r.y);
            r.z = fmaf(s4.x, w0.z, r.z); r.w = fmaf(s4.x, w0.w, r.w);
            r.x = fmaf(s4.y, w1.x, r.x); r.y = fmaf(s4.y, w1.y, r.y);
            r.z = fmaf(s4.y, w1.z, r.z); r.w = fmaf(s4.y, w1.w, r.w);
            r.x = fmaf(s4.z, w2v.x, r.x); r.y = fmaf(s4.z, w2v.y, r.y);
            r.z = fmaf(s4.z, w2v.z, r.z); r.w = fmaf(s4.z, w2v.w, r.w);
            r.x = fmaf(s4.w, w3.x, r.x); r.y = fmaf(s4.w, w3.y, r.y);
            r.z = fmaf(s4.w, w3.z, r.z); r.w = fmaf(s4.w, w3.w, r.w);
        }
        // combine the two half-sums and store from half 0
        {
            const float rx = __shfl_xor(r.x, 32, 64);
            const float ry = __shfl_xor(r.y, 32, 64);
            const float rz = __shfl_xor(r.z, 32, 64);
            const float rw = __shfl_xor(r.w, 32, 64);
            r.x += rx; r.y += ry; r.z += rz; r.w += rw;
        }
        if (half == 0)
            *(float4*)(out0 + (size_t)q * EMBED + dpb) = r;
    }
}

// ---------------------------------------------------------------------------
extern "C" void kernel_launch(void* const* d_in, const int* in_sizes, int n_in,
                              void* d_out, int out_size, void* d_ws, size_t ws_size,
                              hipStream_t stream) {
    const float* query = (const float*)d_in[0];
    const float* value = (const float*)d_in[1];
    const float* refp  = (const float*)d_in[2];
    const float* Woff  = (const float*)d_in[3];
    const float* boff  = (const float*)d_in[4];
    const float* Wattn = (const float*)d_in[5];
    const float* battn = (const float*)d_in[6];
    const float* Wval  = (const float*)d_in[7];
    const float* bval  = (const float*)d_in[8];
    const float* Wout  = (const float*)d_in[9];
    const float* bout  = (const float*)d_in[10];
    const float* Wproj = (const float*)d_in[11];
    // d_in[12] = b_proj: level-constant -> cancels in softmax/argmax, unused.

    float* ws = (float*)d_ws;
    float* ws_v   = ws;                                   // NPIX*128 (pixel-major)
    float* ws_off = ws_v + (size_t)NPIX * EMBED;          // NQ*64
    float* ws_aw  = ws_off + (size_t)NQ * 64;             // NQ*32
    float* ws_u   = ws_aw + (size_t)NQ * 32;              // 128

    float* out0 = (float*)d_out;
    float* out1 = out0 + (size_t)NQ * EMBED;

    hipLaunchKernelGGL(k_prep, dim3(GRID_A + GRID_B + 1), dim3(256), 0, stream,
                       value, Wval, bval, query, Woff, boff, Wattn, battn,
                       Wout, Wproj, ws_v, ws_off, ws_aw, ws_u);
    hipLaunchKernelGGL(k_main, dim3(NQ / 2), dim3(256), 0, stream,
                       query, refp, ws_off, ws_aw, ws_v, ws_u, Wout, bout,
                       out0, out1);
}